// Round 1
// baseline (165.702 us; speedup 1.0000x reference)
//
#include <hip/hip_runtime.h>

#define NB 8
#define NS 2048
#define ND 1024
#define NH 64

typedef __attribute__((ext_vector_type(8))) short short8;
typedef __attribute__((ext_vector_type(4))) float f32x4;

__device__ __forceinline__ unsigned short f2bf(float f) {
    union { float f; unsigned u; } v; v.f = f;
    unsigned r = (v.u + 0x7FFFu + ((v.u >> 16) & 1u)) >> 16;
    return (unsigned short)r;
}

// ---------------------------------------------------------------------------
// Kernel A: fused QKV projection.  x[16384,1024] fp32 @ {Wq,Wk,Wv}^T -> bf16
// q is pre-scaled by 1/sqrt(64). Tile: 64 rows x 192 cols, BK=32, 4 waves.
// ---------------------------------------------------------------------------
__global__ __launch_bounds__(256) void qkv_kernel(
    const float* __restrict__ x,
    const float* __restrict__ Wq, const float* __restrict__ bq,
    const float* __restrict__ Wk, const float* __restrict__ bk,
    const float* __restrict__ Wv, const float* __restrict__ bv,
    unsigned short* __restrict__ q, unsigned short* __restrict__ k,
    unsigned short* __restrict__ v)
{
    __shared__ unsigned short As[64][40];   // [row][k], pad 32->40 (2-way banks)
    __shared__ unsigned short Bs[192][40];  // [n][k] = W[n][k]

    const int t    = threadIdx.x;
    const int wave = t >> 6;
    const int lane = t & 63;
    const int g    = lane >> 4;
    const int li   = lane & 15;
    const int m0   = blockIdx.x * 64;

    f32x4 acc[12];
#pragma unroll
    for (int i = 0; i < 12; ++i) acc[i] = (f32x4)0.f;

    for (int kk = 0; kk < ND / 32; ++kk) {
        // stage A: 64 rows x 32 k
        {
            int r = t >> 5, c = t & 31;
#pragma unroll
            for (int p = 0; p < 8; ++p) {
                float xv = x[(long)(m0 + r + p * 8) * ND + kk * 32 + c];
                As[r + p * 8][c] = f2bf(xv);
            }
        }
        // stage B: 192 rows (q|k|v) x 32 k
        {
            int c = t & 31;
#pragma unroll
            for (int p = 0; p < 24; ++p) {
                int n = p * 8 + (t >> 5);
                const float* W = (n < 64) ? Wq : (n < 128 ? Wk : Wv);
                Bs[n][c] = f2bf(W[(n & 63) * ND + kk * 32 + c]);
            }
        }
        __syncthreads();

        short8 a = *(const short8*)&As[wave * 16 + li][g * 8];
#pragma unroll
        for (int nf = 0; nf < 12; ++nf) {
            short8 b = *(const short8*)&Bs[nf * 16 + li][g * 8];
            acc[nf] = __builtin_amdgcn_mfma_f32_16x16x32_bf16(a, b, acc[nf], 0, 0, 0);
        }
        __syncthreads();
    }

    const float scale = 0.125f;  // 1/sqrt(NH)
#pragma unroll
    for (int nf = 0; nf < 12; ++nf) {
        int col = nf * 16 + li;
        int hh  = col & 63;
#pragma unroll
        for (int i = 0; i < 4; ++i) {
            int row   = m0 + wave * 16 + g * 4 + i;
            float val = acc[nf][i];
            if (col < 64) {
                val = (val + bq[hh]) * scale;
                q[(long)row * 64 + hh] = f2bf(val);
            } else if (col < 128) {
                val += bk[hh];
                k[(long)row * 64 + hh] = f2bf(val);
            } else {
                val += bv[hh];
                v[(long)row * 64 + hh] = f2bf(val);
            }
        }
    }
}

// ---------------------------------------------------------------------------
// Kernel B: causal flash attention. One block = (batch, 64-row q tile),
// 4 waves x 16 q rows. KV tiles of 32 staged in LDS. Online softmax fp32.
// ---------------------------------------------------------------------------
__global__ __launch_bounds__(256) void attn_kernel(
    const unsigned short* __restrict__ q, const unsigned short* __restrict__ k,
    const unsigned short* __restrict__ v, float* __restrict__ O)
{
    __shared__ unsigned short Ks[32][72];      // [kv][feat], stride 144B
    __shared__ unsigned short Vt[64][40];      // [feat][kv], stride 80B
    __shared__ unsigned short Ps[4][16][40];   // per-wave P [q][kv]

    const int t    = threadIdx.x;
    const int wave = t >> 6;
    const int lane = t & 63;
    const int g    = lane >> 4;
    const int li   = lane & 15;
    const int b    = blockIdx.x >> 5;   // NS/64 = 32 q tiles
    const int qt   = blockIdx.x & 31;
    const long base = (long)b * NS * 64;

    // Q fragments for this wave's 16 rows (feats 0..63 in 2 chunks)
    const int qrow = qt * 64 + wave * 16 + li;
    short8 qa0 = *(const short8*)&q[base + (long)qrow * 64 + 0  + g * 8];
    short8 qa1 = *(const short8*)&q[base + (long)qrow * 64 + 32 + g * 8];

    float m_i[4], l_i[4];
    f32x4 oacc[4];
#pragma unroll
    for (int i = 0; i < 4; ++i) { m_i[i] = -1e30f; l_i[i] = 0.f; oacc[i] = (f32x4)0.f; }

    const int ntiles = qt * 2 + 2;  // covers kv 0 .. qt*64+63

    for (int kt = 0; kt < ntiles; ++kt) {
        const int kv0 = kt * 32;
        // ---- stage K (waves 2,3) and V^T (waves 0,1) ----
        if (t < 128) {
            int p  = t >> 3;   // kv pair 0..15
            int fg = t & 7;    // feat group
            short8 v0 = *(const short8*)&v[base + (long)(kv0 + 2 * p)     * 64 + fg * 8];
            short8 v1 = *(const short8*)&v[base + (long)(kv0 + 2 * p + 1) * 64 + fg * 8];
#pragma unroll
            for (int e = 0; e < 8; ++e) {
                unsigned val = (unsigned)(unsigned short)v0[e] |
                               ((unsigned)(unsigned short)v1[e] << 16);
                *(unsigned*)&Vt[fg * 8 + e][2 * p] = val;
            }
        } else {
            int tt = t - 128;
            int r   = tt >> 2;  // kv row 0..31
            int fg2 = tt & 3;   // 16-feat group
            short8 k0 = *(const short8*)&k[base + (long)(kv0 + r) * 64 + fg2 * 16];
            short8 k1 = *(const short8*)&k[base + (long)(kv0 + r) * 64 + fg2 * 16 + 8];
            *(short8*)&Ks[r][fg2 * 16]     = k0;
            *(short8*)&Ks[r][fg2 * 16 + 8] = k1;
        }
        __syncthreads();

        // ---- QK^T: 16 q x 32 kv ----
        f32x4 s0 = (f32x4)0.f, s1 = (f32x4)0.f;
        {
            short8 b00 = *(const short8*)&Ks[li][g * 8];
            short8 b01 = *(const short8*)&Ks[li][32 + g * 8];
            s0 = __builtin_amdgcn_mfma_f32_16x16x32_bf16(qa0, b00, s0, 0, 0, 0);
            s0 = __builtin_amdgcn_mfma_f32_16x16x32_bf16(qa1, b01, s0, 0, 0, 0);
            short8 b10 = *(const short8*)&Ks[16 + li][g * 8];
            short8 b11 = *(const short8*)&Ks[16 + li][32 + g * 8];
            s1 = __builtin_amdgcn_mfma_f32_16x16x32_bf16(qa0, b10, s1, 0, 0, 0);
            s1 = __builtin_amdgcn_mfma_f32_16x16x32_bf16(qa1, b11, s1, 0, 0, 0);
        }

        // ---- causal mask + online softmax ----
        float mx[4];
#pragma unroll
        for (int i = 0; i < 4; ++i) {
            int qg = qt * 64 + wave * 16 + 4 * g + i;
            if (kv0 + li > qg)      s0[i] = -1e30f;
            if (kv0 + 16 + li > qg) s1[i] = -1e30f;
            mx[i] = fmaxf(s0[i], s1[i]);
        }
#pragma unroll
        for (int off = 1; off < 16; off <<= 1) {
#pragma unroll
            for (int i = 0; i < 4; ++i)
                mx[i] = fmaxf(mx[i], __shfl_xor(mx[i], off));
        }
        float pa0[4], pa1[4], rs[4];
#pragma unroll
        for (int i = 0; i < 4; ++i) {
            float mnew  = fmaxf(m_i[i], mx[i]);
            float alpha = __expf(m_i[i] - mnew);
            pa0[i] = __expf(s0[i] - mnew);
            pa1[i] = __expf(s1[i] - mnew);
            m_i[i] = mnew;
            rs[i]  = pa0[i] + pa1[i];
            l_i[i] *= alpha;
#pragma unroll
            for (int nf = 0; nf < 4; ++nf) oacc[nf][i] *= alpha;
        }
#pragma unroll
        for (int off = 1; off < 16; off <<= 1) {
#pragma unroll
            for (int i = 0; i < 4; ++i) rs[i] += __shfl_xor(rs[i], off);
        }
#pragma unroll
        for (int i = 0; i < 4; ++i) l_i[i] += rs[i];

        // ---- P -> LDS (transpose to A-frag layout), then PV ----
#pragma unroll
        for (int i = 0; i < 4; ++i) {
            Ps[wave][4 * g + i][li]      = f2bf(pa0[i]);
            Ps[wave][4 * g + i][16 + li] = f2bf(pa1[i]);
        }
        short8 pfrag = *(const short8*)&Ps[wave][li][g * 8];
#pragma unroll
        for (int nf = 0; nf < 4; ++nf) {
            short8 vfrag = *(const short8*)&Vt[nf * 16 + li][g * 8];
            oacc[nf] = __builtin_amdgcn_mfma_f32_16x16x32_bf16(pfrag, vfrag, oacc[nf], 0, 0, 0);
        }
        __syncthreads();
    }

    // ---- normalize + store O (fp32) ----
#pragma unroll
    for (int nf = 0; nf < 4; ++nf) {
#pragma unroll
        for (int i = 0; i < 4; ++i) {
            int row = qt * 64 + wave * 16 + 4 * g + i;
            O[base + (long)row * 64 + nf * 16 + li] = oacc[nf][i] / l_i[i];
        }
    }
}

// ---------------------------------------------------------------------------
// Kernel C: output projection out = O @ Wo^T + bo  (64x64, VALU)
// ---------------------------------------------------------------------------
__global__ __launch_bounds__(256) void oproj_kernel(
    const float* __restrict__ O, const float* __restrict__ Wo,
    const float* __restrict__ bo, float* __restrict__ out)
{
    __shared__ float Os[64][65];
    __shared__ float Ws[64][65];
    const int t = threadIdx.x;
    const long r0 = (long)blockIdx.x * 64;

#pragma unroll
    for (int p = 0; p < 16; ++p) {
        int idx = p * 256 + t;
        int r = idx >> 6, c = idx & 63;
        Os[r][c] = O[(r0 + r) * 64 + c];
        Ws[r][c] = Wo[r * 64 + c];
    }
    __syncthreads();

#pragma unroll
    for (int p = 0; p < 16; ++p) {
        int idx = p * 256 + t;
        int r = idx >> 6, c = idx & 63;
        float acc = bo[c];
#pragma unroll
        for (int h = 0; h < 64; ++h) acc += Os[r][h] * Ws[c][h];
        out[(r0 + r) * 64 + c] = acc;
    }
}

// ---------------------------------------------------------------------------
extern "C" void kernel_launch(void* const* d_in, const int* in_sizes, int n_in,
                              void* d_out, int out_size, void* d_ws, size_t ws_size,
                              hipStream_t stream)
{
    const float* x  = (const float*)d_in[0];
    const float* Wq = (const float*)d_in[1];
    const float* bq = (const float*)d_in[2];
    const float* Wk = (const float*)d_in[3];
    const float* bk = (const float*)d_in[4];
    const float* Wv = (const float*)d_in[5];
    const float* bv = (const float*)d_in[6];
    const float* Wo = (const float*)d_in[7];
    const float* bo = (const float*)d_in[8];
    float* out = (float*)d_out;

    const size_t M = (size_t)NB * NS;           // 16384
    unsigned short* qb = (unsigned short*)d_ws; // bf16 [M][64]  (2 MB)
    unsigned short* kb = qb + M * 64;
    unsigned short* vb = kb + M * 64;
    float* Ob = (float*)(vb + M * 64);          // fp32 [M][64]  (4 MB)

    qkv_kernel<<<M / 64, 256, 0, stream>>>(x, Wq, bq, Wk, bk, Wv, bv, qb, kb, vb);
    attn_kernel<<<NB * (NS / 64), 256, 0, stream>>>(qb, kb, vb, Ob);
    oproj_kernel<<<M / 64, 256, 0, stream>>>(Ob, Wo, bo, out);
}

// Round 2
// 78.993 us; speedup vs baseline: 2.0977x; 2.0977x over previous
//
#include <hip/hip_runtime.h>

#define NB 8
#define NS 2048
#define ND 1024
#define NH 64
#define NM (NB*NS)   // 16384 rows

typedef __attribute__((ext_vector_type(8))) short short8;
typedef __attribute__((ext_vector_type(4))) short short4v;
typedef __attribute__((ext_vector_type(4))) float f32x4;
typedef __attribute__((ext_vector_type(4))) float f4;

__device__ __forceinline__ unsigned short f2bf(float f) {
    union { float f; unsigned u; } v; v.f = f;
    unsigned r = (v.u + 0x7FFFu + ((v.u >> 16) & 1u)) >> 16;
    return (unsigned short)r;
}

// ---------------------------------------------------------------------------
// Kernel 0: W -> bf16 (q rows pre-scaled by 1/8), bias vector (bq pre-scaled)
// ---------------------------------------------------------------------------
__global__ __launch_bounds__(256) void convw_kernel(
    const float* __restrict__ Wq, const float* __restrict__ bq,
    const float* __restrict__ Wk, const float* __restrict__ bk,
    const float* __restrict__ Wv, const float* __restrict__ bv,
    unsigned short* __restrict__ Wb, float* __restrict__ biasb)
{
    const int row = blockIdx.x;   // 0..191
    const int t = threadIdx.x;    // 0..255
    const float* W = row < 64 ? Wq : (row < 128 ? Wk : Wv);
    const float sc = row < 64 ? 0.125f : 1.0f;
    f4 v = *(const f4*)&W[(size_t)(row & 63) * ND + t * 4];
    short4v o;
#pragma unroll
    for (int j = 0; j < 4; ++j) o[j] = (short)f2bf(v[j] * sc);
    *(short4v*)&Wb[(size_t)row * ND + t * 4] = o;
    if (row == 0 && t < 192) {
        const float* bsrc = t < 64 ? bq : (t < 128 ? bk : bv);
        biasb[t] = bsrc[t & 63] * (t < 64 ? 0.125f : 1.0f);
    }
}

// ---------------------------------------------------------------------------
// Kernel 1: QKV projection.  64 rows x 192 cols per block, BK=64, 8 waves,
// double-buffered LDS, XOR-swizzled chunks. V stored transposed [b][h][s].
// ---------------------------------------------------------------------------
__global__ __launch_bounds__(512) void qkv_kernel(
    const float* __restrict__ x, const unsigned short* __restrict__ Wb,
    const float* __restrict__ biasb,
    unsigned short* __restrict__ q, unsigned short* __restrict__ k,
    unsigned short* __restrict__ vT)
{
    __shared__ unsigned short As[2][64 * 64];
    __shared__ unsigned short Bs[2][192 * 64];

    const int t = threadIdx.x;
    const int lane = t & 63, g = lane >> 4, li = lane & 15;
    const int w = t >> 6, rg = w >> 2, cg = w & 3;
    const int m0 = blockIdx.x * 64;
    const int arow = t >> 3, ach = t & 7;

    f32x4 acc[2][3];
#pragma unroll
    for (int a = 0; a < 2; ++a)
#pragma unroll
        for (int nf = 0; nf < 3; ++nf) acc[a][nf] = (f32x4)0.f;

    f4 a0, a1; short8 breg0, breg1, breg2;

    // prologue: load + commit k-step 0
    {
        const float* p = &x[(size_t)(m0 + arow) * ND + ach * 8];
        a0 = *(const f4*)p; a1 = *(const f4*)(p + 4);
        breg0 = *(const short8*)&Wb[(size_t)((t + 0) >> 3) * ND + ((t + 0) & 7) * 8];
        breg1 = *(const short8*)&Wb[(size_t)((t + 512) >> 3) * ND + ((t + 512) & 7) * 8];
        breg2 = *(const short8*)&Wb[(size_t)((t + 1024) >> 3) * ND + ((t + 1024) & 7) * 8];
        short8 av;
#pragma unroll
        for (int j = 0; j < 4; ++j) { av[j] = (short)f2bf(a0[j]); av[j + 4] = (short)f2bf(a1[j]); }
        *(short8*)&As[0][arow * 64 + ((ach ^ (arow & 7)) << 3)] = av;
        {
            int s0 = t, r0 = s0 >> 3, c0 = s0 & 7;
            *(short8*)&Bs[0][r0 * 64 + ((c0 ^ (r0 & 7)) << 3)] = breg0;
            int s1 = t + 512, r1 = s1 >> 3, c1 = s1 & 7;
            *(short8*)&Bs[0][r1 * 64 + ((c1 ^ (r1 & 7)) << 3)] = breg1;
            int s2 = t + 1024, r2 = s2 >> 3, c2 = s2 & 7;
            *(short8*)&Bs[0][r2 * 64 + ((c2 ^ (r2 & 7)) << 3)] = breg2;
        }
    }
    __syncthreads();

    for (int ks = 0; ks < 16; ++ks) {
        const int cur = ks & 1;
        if (ks < 15) {
            const float* p = &x[(size_t)(m0 + arow) * ND + (ks + 1) * 64 + ach * 8];
            a0 = *(const f4*)p; a1 = *(const f4*)(p + 4);
            breg0 = *(const short8*)&Wb[(size_t)((t + 0) >> 3) * ND + (ks + 1) * 64 + ((t + 0) & 7) * 8];
            breg1 = *(const short8*)&Wb[(size_t)((t + 512) >> 3) * ND + (ks + 1) * 64 + ((t + 512) & 7) * 8];
            breg2 = *(const short8*)&Wb[(size_t)((t + 1024) >> 3) * ND + (ks + 1) * 64 + ((t + 1024) & 7) * 8];
        }
#pragma unroll
        for (int h = 0; h < 2; ++h) {
            short8 af0 = *(const short8*)&As[cur][(rg * 32 + 0 + li) * 64 + (((g + 4 * h) ^ (li & 7)) << 3)];
            short8 af1 = *(const short8*)&As[cur][(rg * 32 + 16 + li) * 64 + (((g + 4 * h) ^ (li & 7)) << 3)];
#pragma unroll
            for (int nf = 0; nf < 3; ++nf) {
                short8 bf = *(const short8*)&Bs[cur][(cg * 48 + nf * 16 + li) * 64 + (((g + 4 * h) ^ (li & 7)) << 3)];
                acc[0][nf] = __builtin_amdgcn_mfma_f32_16x16x32_bf16(af0, bf, acc[0][nf], 0, 0, 0);
                acc[1][nf] = __builtin_amdgcn_mfma_f32_16x16x32_bf16(af1, bf, acc[1][nf], 0, 0, 0);
            }
        }
        if (ks < 15) {
            short8 av;
#pragma unroll
            for (int j = 0; j < 4; ++j) { av[j] = (short)f2bf(a0[j]); av[j + 4] = (short)f2bf(a1[j]); }
            *(short8*)&As[cur ^ 1][arow * 64 + ((ach ^ (arow & 7)) << 3)] = av;
            int s0 = t, r0 = s0 >> 3, c0 = s0 & 7;
            *(short8*)&Bs[cur ^ 1][r0 * 64 + ((c0 ^ (r0 & 7)) << 3)] = breg0;
            int s1 = t + 512, r1 = s1 >> 3, c1 = s1 & 7;
            *(short8*)&Bs[cur ^ 1][r1 * 64 + ((c1 ^ (r1 & 7)) << 3)] = breg1;
            int s2 = t + 1024, r2 = s2 >> 3, c2 = s2 & 7;
            *(short8*)&Bs[cur ^ 1][r2 * 64 + ((c2 ^ (r2 & 7)) << 3)] = breg2;
        }
        __syncthreads();
    }

    // epilogue: bias + store (q,k row-major; v transposed [b][h][s])
#pragma unroll
    for (int nf = 0; nf < 3; ++nf) {
        const int col = cg * 48 + nf * 16 + li;
        const float bias = biasb[col];
#pragma unroll
        for (int a = 0; a < 2; ++a) {
            const int row0 = m0 + rg * 32 + a * 16 + 4 * g;
            if (col < 64) {
#pragma unroll
                for (int i = 0; i < 4; ++i)
                    q[(size_t)(row0 + i) * NH + col] = f2bf(acc[a][nf][i] + bias);
            } else if (col < 128) {
#pragma unroll
                for (int i = 0; i < 4; ++i)
                    k[(size_t)(row0 + i) * NH + (col - 64)] = f2bf(acc[a][nf][i] + bias);
            } else {
                short4v pk;
#pragma unroll
                for (int i = 0; i < 4; ++i) pk[i] = (short)f2bf(acc[a][nf][i] + bias);
                const int bb = row0 >> 11, s = row0 & 2047;
                *(short4v*)&vT[(size_t)(bb * NH + (col - 128)) * NS + s] = pk;
            }
        }
    }
}

// ---------------------------------------------------------------------------
// Kernel 2: split-KV causal flash attention. Block = (batch, q-tile64, chunk).
// 4 waves x 16 q rows. KV tile 64, double-buffered, XOR-swizzled LDS.
// Writes unnormalized partials (O', m, l).
// ---------------------------------------------------------------------------
__global__ __launch_bounds__(256) void attn_kernel(
    const unsigned short* __restrict__ q, const unsigned short* __restrict__ k,
    const unsigned short* __restrict__ vT,
    float* __restrict__ Opart, float* __restrict__ mpart, float* __restrict__ lpart,
    int ctLog, int MAXC)
{
    __shared__ unsigned short Ks[2][64 * 64];
    __shared__ unsigned short Vs[2][64 * 64];
    __shared__ unsigned short Ps[4][16 * 64];

    const int t = threadIdx.x;
    const int w = t >> 6, lane = t & 63, g = lane >> 4, li = lane & 15;
    const int b = blockIdx.x & 7;          // batch -> XCD pinning
    const int pid = blockIdx.x >> 3;
    const int CT = 1 << ctLog;

    int qt = 0, c = 0;
    {
        int acc = 0;
        for (int u = 31; u >= 0; --u) {    // largest-work-first
            int nch = (u + CT) >> ctLog;
            if (pid < acc + nch) { qt = u; c = pid - acc; break; }
            acc += nch;
        }
    }
    const int t0 = c * CT;
    const int rem = qt + 1 - t0;
    const int tcount = rem < CT ? rem : CT;

    const size_t qkbase = (size_t)b * NS * NH;
    const int qrow = qt * 64 + w * 16 + li;
    const short8 qa0 = *(const short8*)&q[qkbase + (size_t)qrow * NH + g * 8];
    const short8 qa1 = *(const short8*)&q[qkbase + (size_t)qrow * NH + 32 + g * 8];

    float m_i[4], l_i[4]; f32x4 oacc[4];
#pragma unroll
    for (int i = 0; i < 4; ++i) { m_i[i] = -1e30f; l_i[i] = 0.f; oacc[i] = (f32x4)0.f; }

    const int srow = t >> 3, sch = t & 7;
    short8 kreg0, kreg1, vreg0, vreg1;

    // prologue: stage tile 0
    {
        const int kv0 = t0 * 64;
        kreg0 = *(const short8*)&k[qkbase + (size_t)(kv0 + srow) * NH + sch * 8];
        kreg1 = *(const short8*)&k[qkbase + (size_t)(kv0 + srow + 32) * NH + sch * 8];
        vreg0 = *(const short8*)&vT[(size_t)(b * NH + srow) * NS + kv0 + sch * 8];
        vreg1 = *(const short8*)&vT[(size_t)(b * NH + srow + 32) * NS + kv0 + sch * 8];
        *(short8*)&Ks[0][srow * 64 + ((sch ^ (srow & 7)) << 3)] = kreg0;
        *(short8*)&Ks[0][(srow + 32) * 64 + ((sch ^ (srow & 7)) << 3)] = kreg1;
        *(short8*)&Vs[0][srow * 64 + ((sch ^ (srow & 7)) << 3)] = vreg0;
        *(short8*)&Vs[0][(srow + 32) * 64 + ((sch ^ (srow & 7)) << 3)] = vreg1;
    }
    __syncthreads();

    for (int tt = 0; tt < tcount; ++tt) {
        const int cur = tt & 1;
        const int kv0 = (t0 + tt) * 64;
        if (tt + 1 < tcount) {   // issue next-tile loads early (T14)
            const int nv0 = kv0 + 64;
            kreg0 = *(const short8*)&k[qkbase + (size_t)(nv0 + srow) * NH + sch * 8];
            kreg1 = *(const short8*)&k[qkbase + (size_t)(nv0 + srow + 32) * NH + sch * 8];
            vreg0 = *(const short8*)&vT[(size_t)(b * NH + srow) * NS + nv0 + sch * 8];
            vreg1 = *(const short8*)&vT[(size_t)(b * NH + srow + 32) * NS + nv0 + sch * 8];
        }
        // ---- QK^T: 16 q x 64 kv ----
        f32x4 s[4];
#pragma unroll
        for (int c4 = 0; c4 < 4; ++c4) {
            s[c4] = (f32x4)0.f;
            const int krow = 16 * c4 + li;
            short8 kf0 = *(const short8*)&Ks[cur][krow * 64 + ((g ^ (li & 7)) << 3)];
            s[c4] = __builtin_amdgcn_mfma_f32_16x16x32_bf16(qa0, kf0, s[c4], 0, 0, 0);
            short8 kf1 = *(const short8*)&Ks[cur][krow * 64 + (((g + 4) ^ (li & 7)) << 3)];
            s[c4] = __builtin_amdgcn_mfma_f32_16x16x32_bf16(qa1, kf1, s[c4], 0, 0, 0);
        }
        // ---- causal mask: only the diagonal tile needs it ----
        if (kv0 == qt * 64) {
#pragma unroll
            for (int c4 = 0; c4 < 4; ++c4)
#pragma unroll
                for (int i = 0; i < 4; ++i)
                    if (16 * c4 + li > w * 16 + 4 * g + i) s[c4][i] = -1e30f;
        }
        // ---- online softmax (fp32) ----
        float mx[4];
#pragma unroll
        for (int i = 0; i < 4; ++i)
            mx[i] = fmaxf(fmaxf(s[0][i], s[1][i]), fmaxf(s[2][i], s[3][i]));
#pragma unroll
        for (int off = 1; off < 16; off <<= 1)
#pragma unroll
            for (int i = 0; i < 4; ++i) mx[i] = fmaxf(mx[i], __shfl_xor(mx[i], off));

        float p[4][4], rs[4];
#pragma unroll
        for (int i = 0; i < 4; ++i) {
            const float mnew = fmaxf(m_i[i], mx[i]);
            const float alpha = __expf(m_i[i] - mnew);
            m_i[i] = mnew;
            rs[i] = 0.f;
#pragma unroll
            for (int c4 = 0; c4 < 4; ++c4) { p[c4][i] = __expf(s[c4][i] - mnew); rs[i] += p[c4][i]; }
            l_i[i] *= alpha;
#pragma unroll
            for (int nf = 0; nf < 4; ++nf) oacc[nf][i] *= alpha;
        }
#pragma unroll
        for (int off = 1; off < 16; off <<= 1)
#pragma unroll
            for (int i = 0; i < 4; ++i) rs[i] += __shfl_xor(rs[i], off);
#pragma unroll
        for (int i = 0; i < 4; ++i) l_i[i] += rs[i];

        // ---- P -> per-wave LDS (swizzled), then PV ----
#pragma unroll
        for (int c4 = 0; c4 < 4; ++c4)
#pragma unroll
            for (int i = 0; i < 4; ++i) {
                const int prow = 4 * g + i;
                const int chunk = 2 * c4 + (li >> 3);
                Ps[w][prow * 64 + ((chunk ^ (prow & 7)) << 3) + (li & 7)] = f2bf(p[c4][i]);
            }
        short8 pf0 = *(const short8*)&Ps[w][li * 64 + ((g ^ (li & 7)) << 3)];
        short8 pf1 = *(const short8*)&Ps[w][li * 64 + (((g + 4) ^ (li & 7)) << 3)];
#pragma unroll
        for (int nf = 0; nf < 4; ++nf) {
            const int vrow = nf * 16 + li;
            short8 vf0 = *(const short8*)&Vs[cur][vrow * 64 + ((g ^ (li & 7)) << 3)];
            short8 vf1 = *(const short8*)&Vs[cur][vrow * 64 + (((g + 4) ^ (li & 7)) << 3)];
            oacc[nf] = __builtin_amdgcn_mfma_f32_16x16x32_bf16(pf0, vf0, oacc[nf], 0, 0, 0);
            oacc[nf] = __builtin_amdgcn_mfma_f32_16x16x32_bf16(pf1, vf1, oacc[nf], 0, 0, 0);
        }
        if (tt + 1 < tcount) {   // commit next tile late
            *(short8*)&Ks[cur ^ 1][srow * 64 + ((sch ^ (srow & 7)) << 3)] = kreg0;
            *(short8*)&Ks[cur ^ 1][(srow + 32) * 64 + ((sch ^ (srow & 7)) << 3)] = kreg1;
            *(short8*)&Vs[cur ^ 1][srow * 64 + ((sch ^ (srow & 7)) << 3)] = vreg0;
            *(short8*)&Vs[cur ^ 1][(srow + 32) * 64 + ((sch ^ (srow & 7)) << 3)] = vreg1;
        }
        __syncthreads();
    }

    // ---- write partials ----
    const size_t slot = (size_t)((b * 32 + qt) * MAXC + c);
    float* Op = Opart + slot * 4096;
#pragma unroll
    for (int nf = 0; nf < 4; ++nf)
#pragma unroll
        for (int i = 0; i < 4; ++i)
            Op[(w * 16 + 4 * g + i) * 64 + nf * 16 + li] = oacc[nf][i];
    if (li == 0) {
#pragma unroll
        for (int i = 0; i < 4; ++i) {
            mpart[slot * 64 + w * 16 + 4 * g + i] = m_i[i];
            lpart[slot * 64 + w * 16 + 4 * g + i] = l_i[i];
        }
    }
}

// ---------------------------------------------------------------------------
// Kernel 3: combine partials + fused output projection (out = O @ Wo^T + bo)
// ---------------------------------------------------------------------------
__global__ __launch_bounds__(256) void combine_kernel(
    const float* __restrict__ Opart, const float* __restrict__ mpart,
    const float* __restrict__ lpart, const float* __restrict__ Wo,
    const float* __restrict__ bo, float* __restrict__ out,
    int ctLog, int MAXC)
{
    __shared__ float Ws[64][68];
    __shared__ float Osm[64][68];
    __shared__ float Wc[8][64];
    __shared__ float Linv[64];

    const int t = threadIdx.x;
    const int b = blockIdx.x >> 5, qt = blockIdx.x & 31;
    const int CT = 1 << ctLog;
    const int nch = (qt + CT) >> ctLog;
    const size_t base_slot = (size_t)(b * 32 + qt) * MAXC;

#pragma unroll
    for (int pp = 0; pp < 16; ++pp) {
        const int idx = pp * 256 + t;
        Ws[idx >> 6][idx & 63] = Wo[idx];
    }
    if (t < 64) {
        float M = -1e30f;
        for (int cc = 0; cc < nch; ++cc)
            M = fmaxf(M, mpart[(base_slot + cc) * 64 + t]);
        float L = 0.f;
        for (int cc = 0; cc < nch; ++cc) {
            const float wv = __expf(mpart[(base_slot + cc) * 64 + t] - M);
            Wc[cc][t] = wv;
            L += wv * lpart[(base_slot + cc) * 64 + t];
        }
        Linv[t] = 1.f / L;
    }
    __syncthreads();
#pragma unroll
    for (int pp = 0; pp < 16; ++pp) {
        const int idx = pp * 256 + t;
        const int r = idx >> 6, col = idx & 63;
        float acc = 0.f;
        for (int cc = 0; cc < nch; ++cc)
            acc += Wc[cc][r] * Opart[(base_slot + cc) * 4096 + idx];
        Osm[r][col] = acc * Linv[r];
    }
    __syncthreads();
    const int oc = t & 63;
    const int rw = (t >> 6) * 16;
    float acc[16];
#pragma unroll
    for (int rr = 0; rr < 16; ++rr) acc[rr] = 0.f;
#pragma unroll
    for (int hb = 0; hb < 8; ++hb) {
        const f4 wv0 = *(const f4*)&Ws[oc][hb * 8];
        const f4 wv1 = *(const f4*)&Ws[oc][hb * 8 + 4];
#pragma unroll
        for (int rr = 0; rr < 16; ++rr) {
            const f4 ov0 = *(const f4*)&Osm[rw + rr][hb * 8];
            const f4 ov1 = *(const f4*)&Osm[rw + rr][hb * 8 + 4];
#pragma unroll
            for (int j = 0; j < 4; ++j)
                acc[rr] += ov0[j] * wv0[j] + ov1[j] * wv1[j];
        }
    }
    const float bias = bo[oc];
#pragma unroll
    for (int rr = 0; rr < 16; ++rr)
        out[((size_t)b * NS + qt * 64 + rw + rr) * 64 + oc] = acc[rr] + bias;
}

// ---------------------------------------------------------------------------
extern "C" void kernel_launch(void* const* d_in, const int* in_sizes, int n_in,
                              void* d_out, int out_size, void* d_ws, size_t ws_size,
                              hipStream_t stream)
{
    const float* x  = (const float*)d_in[0];
    const float* Wq = (const float*)d_in[1];
    const float* bq = (const float*)d_in[2];
    const float* Wk = (const float*)d_in[3];
    const float* bk = (const float*)d_in[4];
    const float* Wv = (const float*)d_in[5];
    const float* bv = (const float*)d_in[6];
    const float* Wo = (const float*)d_in[7];
    const float* bo = (const float*)d_in[8];
    float* out = (float*)d_out;

    size_t off = 0;
    auto alloc = [&](size_t bytes) {
        char* p = (char*)d_ws + off;
        off += (bytes + 255) & ~(size_t)255;
        return (void*)p;
    };
    unsigned short* qb  = (unsigned short*)alloc((size_t)NM * NH * 2);
    unsigned short* kb  = (unsigned short*)alloc((size_t)NM * NH * 2);
    unsigned short* vtb = (unsigned short*)alloc((size_t)NM * NH * 2);
    unsigned short* Wb  = (unsigned short*)alloc((size_t)192 * ND * 2);
    float* biasb = (float*)alloc(192 * 4);
    const size_t base = off;

    // pick KV-chunk size by workspace: prefer CT=8 (640 blocks), fall back.
    int ctLog = 5, MAXC = 1;
    const int cands[3] = {3, 4, 5};
    for (int ci = 0; ci < 3; ++ci) {
        const int cl = cands[ci];
        const int mc = (31 >> cl) + 1;
        const size_t nslot = (size_t)256 * mc;
        const size_t need = base + nslot * 4096 * 4 + 2 * nslot * 64 * 4 + 4096;
        if (need <= ws_size) { ctLog = cl; MAXC = mc; break; }
    }
    const size_t NSLOT = (size_t)256 * MAXC;
    float* Opart = (float*)alloc(NSLOT * 4096 * 4);
    float* mpart = (float*)alloc(NSLOT * 64 * 4);
    float* lpart = (float*)alloc(NSLOT * 64 * 4);

    const int CT = 1 << ctLog;
    int NCperB = 0;
    for (int qt = 0; qt < 32; ++qt) NCperB += (qt + CT) >> ctLog;

    convw_kernel<<<192, 256, 0, stream>>>(Wq, bq, Wk, bk, Wv, bv, Wb, biasb);
    qkv_kernel<<<NM / 64, 512, 0, stream>>>(x, Wb, biasb, qb, kb, vtb);
    attn_kernel<<<8 * NCperB, 256, 0, stream>>>(qb, kb, vtb, Opart, mpart, lpart, ctLog, MAXC);
    combine_kernel<<<256, 256, 0, stream>>>(Opart, mpart, lpart, Wo, bo, out, ctLog, MAXC);
}

// Round 3
// 50.208 us; speedup vs baseline: 3.3003x; 1.5733x over previous
//
#include <hip/hip_runtime.h>
#include <hip/hip_bf16.h>

#define NB 8
#define NS 2048
#define ND 1024
#define NH 64
#define NM (NB*NS)   // 16384 rows

typedef __attribute__((ext_vector_type(8))) short short8;
typedef __attribute__((ext_vector_type(4))) short short4v;
typedef __attribute__((ext_vector_type(4))) float f32x4;
typedef __attribute__((ext_vector_type(4))) float f4;

// q pre-scale: fold 1/sqrt(64) and log2(e) so attention uses exp2 directly.
#define QSCALE (0.125f * 1.44269504088896340736f)

__device__ __forceinline__ unsigned short f2bf(float f) {
    union { __hip_bfloat16 h; unsigned short u; } cv;
    cv.h = __float2bfloat16(f);   // HW RTNE convert
    return cv.u;
}

// ---------------------------------------------------------------------------
// Kernel 0: weights -> bf16. Rows 0..63 Wq (pre-scaled), 64..127 Wk,
// 128..191 Wv, 192..255 Wo (64x64). Bias vector for q/k/v.
// ---------------------------------------------------------------------------
__global__ __launch_bounds__(256) void convw_kernel(
    const float* __restrict__ Wq, const float* __restrict__ bq,
    const float* __restrict__ Wk, const float* __restrict__ bk,
    const float* __restrict__ Wv, const float* __restrict__ bv,
    const float* __restrict__ Wo,
    unsigned short* __restrict__ Wb, unsigned short* __restrict__ Wob,
    float* __restrict__ biasb)
{
    const int row = blockIdx.x;   // 0..255
    const int t = threadIdx.x;    // 0..255
    if (row < 192) {
        const float* W = row < 64 ? Wq : (row < 128 ? Wk : Wv);
        const float sc = row < 64 ? QSCALE : 1.0f;
        f4 v = *(const f4*)&W[(size_t)(row & 63) * ND + t * 4];
        short4v o;
#pragma unroll
        for (int j = 0; j < 4; ++j) o[j] = (short)f2bf(v[j] * sc);
        *(short4v*)&Wb[(size_t)row * ND + t * 4] = o;
        if (row == 0 && t < 192) {
            const float* bsrc = t < 64 ? bq : (t < 128 ? bk : bv);
            biasb[t] = bsrc[t & 63] * (t < 64 ? QSCALE : 1.0f);
        }
    } else if (t < 16) {
        f4 v = *(const f4*)&Wo[(size_t)(row - 192) * 64 + t * 4];
        short4v o;
#pragma unroll
        for (int j = 0; j < 4; ++j) o[j] = (short)f2bf(v[j]);
        *(short4v*)&Wob[(size_t)(row - 192) * 64 + t * 4] = o;
    }
}

// ---------------------------------------------------------------------------
// Kernel 1: QKV projection. 64 rows x 192 cols, BK=64, 8 waves, LDS dbuf,
// 2-deep register prefetch. V stored transposed [b][h][s].
// ---------------------------------------------------------------------------
__global__ __launch_bounds__(512) void qkv_kernel(
    const float* __restrict__ x, const unsigned short* __restrict__ Wb,
    const float* __restrict__ biasb,
    unsigned short* __restrict__ q, unsigned short* __restrict__ k,
    unsigned short* __restrict__ vT)
{
    __shared__ unsigned short As[2][64 * 64];
    __shared__ unsigned short Bs[2][192 * 64];

    const int t = threadIdx.x;
    const int lane = t & 63, g = lane >> 4, li = lane & 15;
    const int w = t >> 6, rg = w >> 2, cg = w & 3;
    const int m0 = blockIdx.x * 64;
    const int arow = t >> 3, ach = t & 7;

    f32x4 acc[2][3];
#pragma unroll
    for (int a = 0; a < 2; ++a)
#pragma unroll
        for (int nf = 0; nf < 3; ++nf) acc[a][nf] = (f32x4)0.f;

    f4 xa[2][2]; short8 wr[2][3];

#define QKV_LOAD(KS, SL)                                                          \
    {                                                                             \
        const float* p_ = &x[(size_t)(m0 + arow) * ND + (KS) * 64 + ach * 8];     \
        xa[SL][0] = *(const f4*)p_; xa[SL][1] = *(const f4*)(p_ + 4);             \
        wr[SL][0] = *(const short8*)&Wb[(size_t)(t >> 3) * ND + (KS) * 64 + (t & 7) * 8];                  \
        wr[SL][1] = *(const short8*)&Wb[(size_t)((t + 512) >> 3) * ND + (KS) * 64 + ((t + 512) & 7) * 8];  \
        wr[SL][2] = *(const short8*)&Wb[(size_t)((t + 1024) >> 3) * ND + (KS) * 64 + ((t + 1024) & 7) * 8];\
    }

#define QKV_COMMIT(SL, BUF)                                                       \
    {                                                                             \
        short8 av_;                                                               \
        for (int j_ = 0; j_ < 4; ++j_) {                                          \
            av_[j_] = (short)f2bf(xa[SL][0][j_]);                                 \
            av_[j_ + 4] = (short)f2bf(xa[SL][1][j_]);                             \
        }                                                                         \
        *(short8*)&As[BUF][arow * 64 + ((ach ^ (arow & 7)) << 3)] = av_;          \
        int r0_ = t >> 3, c0_ = t & 7;                                            \
        *(short8*)&Bs[BUF][r0_ * 64 + ((c0_ ^ (r0_ & 7)) << 3)] = wr[SL][0];      \
        int r1_ = (t + 512) >> 3, c1_ = (t + 512) & 7;                            \
        *(short8*)&Bs[BUF][r1_ * 64 + ((c1_ ^ (r1_ & 7)) << 3)] = wr[SL][1];      \
        int r2_ = (t + 1024) >> 3, c2_ = (t + 1024) & 7;                          \
        *(short8*)&Bs[BUF][r2_ * 64 + ((c2_ ^ (r2_ & 7)) << 3)] = wr[SL][2];      \
    }

    QKV_LOAD(0, 0);
    QKV_LOAD(1, 1);
    QKV_COMMIT(0, 0);
    __syncthreads();

#pragma unroll
    for (int ks = 0; ks < 16; ++ks) {
        const int cur = ks & 1;
        if (ks < 14) QKV_LOAD(ks + 2, cur);
#pragma unroll
        for (int h = 0; h < 2; ++h) {
            short8 af0 = *(const short8*)&As[cur][(rg * 32 + 0 + li) * 64 + (((g + 4 * h) ^ (li & 7)) << 3)];
            short8 af1 = *(const short8*)&As[cur][(rg * 32 + 16 + li) * 64 + (((g + 4 * h) ^ (li & 7)) << 3)];
#pragma unroll
            for (int nf = 0; nf < 3; ++nf) {
                short8 bf = *(const short8*)&Bs[cur][(cg * 48 + nf * 16 + li) * 64 + (((g + 4 * h) ^ (li & 7)) << 3)];
                acc[0][nf] = __builtin_amdgcn_mfma_f32_16x16x32_bf16(af0, bf, acc[0][nf], 0, 0, 0);
                acc[1][nf] = __builtin_amdgcn_mfma_f32_16x16x32_bf16(af1, bf, acc[1][nf], 0, 0, 0);
            }
        }
        if (ks < 15) QKV_COMMIT((ks + 1) & 1, cur ^ 1);
        __syncthreads();
    }

    // epilogue: bias + store (q,k row-major; v transposed [b][h][s])
#pragma unroll
    for (int nf = 0; nf < 3; ++nf) {
        const int col = cg * 48 + nf * 16 + li;
        const float bias = biasb[col];
#pragma unroll
        for (int a = 0; a < 2; ++a) {
            const int row0 = m0 + rg * 32 + a * 16 + 4 * g;
            if (col < 64) {
#pragma unroll
                for (int i = 0; i < 4; ++i)
                    q[(size_t)(row0 + i) * NH + col] = f2bf(acc[a][nf][i] + bias);
            } else if (col < 128) {
#pragma unroll
                for (int i = 0; i < 4; ++i)
                    k[(size_t)(row0 + i) * NH + (col - 64)] = f2bf(acc[a][nf][i] + bias);
            } else {
                short4v pk;
#pragma unroll
                for (int i = 0; i < 4; ++i) pk[i] = (short)f2bf(acc[a][nf][i] + bias);
                const int bb = row0 >> 11, s = row0 & 2047;
                *(short4v*)&vT[(size_t)(bb * NH + (col - 128)) * NS + s] = pk;
            }
        }
    }
}

// ---------------------------------------------------------------------------
// Kernel 2: split-KV causal attention, NO-MAX softmax (p = exp2(s), clamp 80).
// Block = (batch, q-tile64, chunk). 4 waves x 16 q rows. KV tile 64, dbuf.
// Writes unnormalized O' and row-sums l.
// ---------------------------------------------------------------------------
__global__ __launch_bounds__(256) void attn_kernel(
    const unsigned short* __restrict__ q, const unsigned short* __restrict__ k,
    const unsigned short* __restrict__ vT,
    float* __restrict__ Opart, float* __restrict__ lpart,
    int ctLog, int MAXC)
{
    __shared__ unsigned short Ks[2][64 * 64];
    __shared__ unsigned short Vs[2][64 * 64];
    __shared__ unsigned short Ps[4][16 * 64];

    const int t = threadIdx.x;
    const int w = t >> 6, lane = t & 63, g = lane >> 4, li = lane & 15;
    const int b = blockIdx.x & 7;          // batch -> XCD pinning
    const int pid = blockIdx.x >> 3;
    const int CT = 1 << ctLog;

    int qt = 0, c = 0;
    {
        int acc = 0;
        for (int u = 31; u >= 0; --u) {    // largest-work-first
            int nch = (u + CT) >> ctLog;
            if (pid < acc + nch) { qt = u; c = pid - acc; break; }
            acc += nch;
        }
    }
    const int t0 = c * CT;
    const int rem = qt + 1 - t0;
    const int tcount = rem < CT ? rem : CT;

    const size_t qkbase = (size_t)b * NS * NH;
    const int qrow = qt * 64 + w * 16 + li;
    const short8 qa0 = *(const short8*)&q[qkbase + (size_t)qrow * NH + g * 8];
    const short8 qa1 = *(const short8*)&q[qkbase + (size_t)qrow * NH + 32 + g * 8];

    float l_i[4]; f32x4 oacc[4];
#pragma unroll
    for (int i = 0; i < 4; ++i) { l_i[i] = 0.f; oacc[i] = (f32x4)0.f; }

    const int srow = t >> 3, sch = t & 7;
    short8 kreg0, kreg1, vreg0, vreg1;

    {
        const int kv0 = t0 * 64;
        kreg0 = *(const short8*)&k[qkbase + (size_t)(kv0 + srow) * NH + sch * 8];
        kreg1 = *(const short8*)&k[qkbase + (size_t)(kv0 + srow + 32) * NH + sch * 8];
        vreg0 = *(const short8*)&vT[(size_t)(b * NH + srow) * NS + kv0 + sch * 8];
        vreg1 = *(const short8*)&vT[(size_t)(b * NH + srow + 32) * NS + kv0 + sch * 8];
        *(short8*)&Ks[0][srow * 64 + ((sch ^ (srow & 7)) << 3)] = kreg0;
        *(short8*)&Ks[0][(srow + 32) * 64 + ((sch ^ (srow & 7)) << 3)] = kreg1;
        *(short8*)&Vs[0][srow * 64 + ((sch ^ (srow & 7)) << 3)] = vreg0;
        *(short8*)&Vs[0][(srow + 32) * 64 + ((sch ^ (srow & 7)) << 3)] = vreg1;
    }
    __syncthreads();

    for (int tt = 0; tt < tcount; ++tt) {
        const int cur = tt & 1;
        const int kv0 = (t0 + tt) * 64;
        if (tt + 1 < tcount) {   // issue next-tile loads early (T14)
            const int nv0 = kv0 + 64;
            kreg0 = *(const short8*)&k[qkbase + (size_t)(nv0 + srow) * NH + sch * 8];
            kreg1 = *(const short8*)&k[qkbase + (size_t)(nv0 + srow + 32) * NH + sch * 8];
            vreg0 = *(const short8*)&vT[(size_t)(b * NH + srow) * NS + nv0 + sch * 8];
            vreg1 = *(const short8*)&vT[(size_t)(b * NH + srow + 32) * NS + nv0 + sch * 8];
        }
        // ---- QK^T: 16 q x 64 kv (scores already in log2 domain) ----
        f32x4 s[4];
#pragma unroll
        for (int c4 = 0; c4 < 4; ++c4) {
            s[c4] = (f32x4)0.f;
            const int krow = 16 * c4 + li;
            short8 kf0 = *(const short8*)&Ks[cur][krow * 64 + ((g ^ (li & 7)) << 3)];
            s[c4] = __builtin_amdgcn_mfma_f32_16x16x32_bf16(qa0, kf0, s[c4], 0, 0, 0);
            short8 kf1 = *(const short8*)&Ks[cur][krow * 64 + (((g + 4) ^ (li & 7)) << 3)];
            s[c4] = __builtin_amdgcn_mfma_f32_16x16x32_bf16(qa1, kf1, s[c4], 0, 0, 0);
        }
        // ---- causal mask: only the diagonal tile ----
        if (kv0 == qt * 64) {
#pragma unroll
            for (int c4 = 0; c4 < 4; ++c4)
#pragma unroll
                for (int i = 0; i < 4; ++i)
                    if (16 * c4 + li > w * 16 + 4 * g + i) s[c4][i] = -1e30f;
        }
        // ---- no-max softmax: p = exp2(min(s,80)), defer row-sum reduce ----
        float p[4][4];
#pragma unroll
        for (int c4 = 0; c4 < 4; ++c4)
#pragma unroll
            for (int i = 0; i < 4; ++i)
                p[c4][i] = exp2f(fminf(s[c4][i], 80.f));
#pragma unroll
        for (int i = 0; i < 4; ++i)
            l_i[i] += (p[0][i] + p[1][i]) + (p[2][i] + p[3][i]);

        // ---- P -> per-wave LDS (swizzled), then PV ----
#pragma unroll
        for (int c4 = 0; c4 < 4; ++c4)
#pragma unroll
            for (int i = 0; i < 4; ++i) {
                const int prow = 4 * g + i;
                const int chunk = 2 * c4 + (li >> 3);
                Ps[w][prow * 64 + ((chunk ^ (prow & 7)) << 3) + (li & 7)] = f2bf(p[c4][i]);
            }
        short8 pf0 = *(const short8*)&Ps[w][li * 64 + ((g ^ (li & 7)) << 3)];
        short8 pf1 = *(const short8*)&Ps[w][li * 64 + (((g + 4) ^ (li & 7)) << 3)];
#pragma unroll
        for (int nf = 0; nf < 4; ++nf) {
            const int vrow = nf * 16 + li;
            short8 vf0 = *(const short8*)&Vs[cur][vrow * 64 + ((g ^ (li & 7)) << 3)];
            short8 vf1 = *(const short8*)&Vs[cur][vrow * 64 + (((g + 4) ^ (li & 7)) << 3)];
            oacc[nf] = __builtin_amdgcn_mfma_f32_16x16x32_bf16(pf0, vf0, oacc[nf], 0, 0, 0);
            oacc[nf] = __builtin_amdgcn_mfma_f32_16x16x32_bf16(pf1, vf1, oacc[nf], 0, 0, 0);
        }
        if (tt + 1 < tcount) {   // commit next tile late
            *(short8*)&Ks[cur ^ 1][srow * 64 + ((sch ^ (srow & 7)) << 3)] = kreg0;
            *(short8*)&Ks[cur ^ 1][(srow + 32) * 64 + ((sch ^ (srow & 7)) << 3)] = kreg1;
            *(short8*)&Vs[cur ^ 1][srow * 64 + ((sch ^ (srow & 7)) << 3)] = vreg0;
            *(short8*)&Vs[cur ^ 1][(srow + 32) * 64 + ((sch ^ (srow & 7)) << 3)] = vreg1;
        }
        __syncthreads();
    }

    // ---- one cross-lane l reduction per block (was 2 per tile) ----
#pragma unroll
    for (int off = 1; off < 16; off <<= 1)
#pragma unroll
        for (int i = 0; i < 4; ++i) l_i[i] += __shfl_xor(l_i[i], off);

    const size_t slot = (size_t)((b * 32 + qt) * MAXC + c);
    float* Op = Opart + slot * 4096;
#pragma unroll
    for (int nf = 0; nf < 4; ++nf)
#pragma unroll
        for (int i = 0; i < 4; ++i)
            Op[(w * 16 + 4 * g + i) * 64 + nf * 16 + li] = oacc[nf][i];
    if (li == 0) {
#pragma unroll
        for (int i = 0; i < 4; ++i)
            lpart[slot * 64 + w * 16 + 4 * g + i] = l_i[i];
    }
}

// ---------------------------------------------------------------------------
// Kernel 3: combine partials + MFMA output projection (out = O @ Wo^T + bo)
// ---------------------------------------------------------------------------
__global__ __launch_bounds__(256) void combine_kernel(
    const float* __restrict__ Opart, const float* __restrict__ lpart,
    const unsigned short* __restrict__ Wob, const float* __restrict__ bo,
    float* __restrict__ out, int ctLog, int MAXC)
{
    __shared__ unsigned short Osm[64 * 64];
    __shared__ float Linv[64];

    const int t = threadIdx.x;
    const int b = blockIdx.x & 7, qt = blockIdx.x >> 3;   // XCD-pinned to attn
    const int CT = 1 << ctLog;
    const int nch = (qt + CT) >> ctLog;
    const size_t base_slot = (size_t)(b * 32 + qt) * MAXC;

    if (t < 64) {
        float L = 0.f;
        for (int cc = 0; cc < nch; ++cc)
            L += lpart[(base_slot + cc) * 64 + t];
        Linv[t] = 1.f / L;
    }

    // accumulate O' across chunks: thread owns row r, 16 cols
    const int r = t >> 2, c0 = (t & 3) * 16;
    f4 a0 = (f4)0.f, a1 = (f4)0.f, a2 = (f4)0.f, a3 = (f4)0.f;
    for (int cc = 0; cc < nch; ++cc) {
        const float* P = Opart + (base_slot + cc) * 4096 + r * 64 + c0;
        a0 += *(const f4*)P; a1 += *(const f4*)(P + 4);
        a2 += *(const f4*)(P + 8); a3 += *(const f4*)(P + 12);
    }
    __syncthreads();
    {
        const float sc = Linv[r];
        short8 o0, o1;
#pragma unroll
        for (int j = 0; j < 4; ++j) {
            o0[j] = (short)f2bf(a0[j] * sc); o0[j + 4] = (short)f2bf(a1[j] * sc);
            o1[j] = (short)f2bf(a2[j] * sc); o1[j + 4] = (short)f2bf(a3[j] * sc);
        }
        const int ch0 = (t & 3) * 2;
        *(short8*)&Osm[r * 64 + ((ch0 ^ (r & 7)) << 3)] = o0;
        *(short8*)&Osm[r * 64 + (((ch0 + 1) ^ (r & 7)) << 3)] = o1;
    }
    __syncthreads();

    // oproj: 4 waves x 16 rows, MFMA, B = Wo rows (bf16) straight from global
    const int w = t >> 6, lane = t & 63, g = lane >> 4, li = lane & 15;
    f32x4 acc[4];
#pragma unroll
    for (int nf = 0; nf < 4; ++nf) acc[nf] = (f32x4)0.f;
#pragma unroll
    for (int s = 0; s < 2; ++s) {
        short8 af = *(const short8*)&Osm[(w * 16 + li) * 64 + (((g + 4 * s) ^ (li & 7)) << 3)];
#pragma unroll
        for (int nf = 0; nf < 4; ++nf) {
            short8 bf = *(const short8*)&Wob[(size_t)(nf * 16 + li) * 64 + s * 32 + g * 8];
            acc[nf] = __builtin_amdgcn_mfma_f32_16x16x32_bf16(af, bf, acc[nf], 0, 0, 0);
        }
    }
#pragma unroll
    for (int nf = 0; nf < 4; ++nf) {
        const float bias = bo[nf * 16 + li];
#pragma unroll
        for (int i = 0; i < 4; ++i) {
            const size_t row = (size_t)b * NS + qt * 64 + w * 16 + 4 * g + i;
            out[row * 64 + nf * 16 + li] = acc[nf][i] + bias;
        }
    }
}

// ---------------------------------------------------------------------------
extern "C" void kernel_launch(void* const* d_in, const int* in_sizes, int n_in,
                              void* d_out, int out_size, void* d_ws, size_t ws_size,
                              hipStream_t stream)
{
    const float* x  = (const float*)d_in[0];
    const float* Wq = (const float*)d_in[1];
    const float* bq = (const float*)d_in[2];
    const float* Wk = (const float*)d_in[3];
    const float* bk = (const float*)d_in[4];
    const float* Wv = (const float*)d_in[5];
    const float* bv = (const float*)d_in[6];
    const float* Wo = (const float*)d_in[7];
    const float* bo = (const float*)d_in[8];
    float* out = (float*)d_out;

    size_t off = 0;
    auto alloc = [&](size_t bytes) {
        char* p = (char*)d_ws + off;
        off += (bytes + 255) & ~(size_t)255;
        return (void*)p;
    };
    unsigned short* qb  = (unsigned short*)alloc((size_t)NM * NH * 2);
    unsigned short* kb  = (unsigned short*)alloc((size_t)NM * NH * 2);
    unsigned short* vtb = (unsigned short*)alloc((size_t)NM * NH * 2);
    unsigned short* Wb  = (unsigned short*)alloc((size_t)192 * ND * 2);
    unsigned short* Wob = (unsigned short*)alloc((size_t)64 * 64 * 2);
    float* biasb = (float*)alloc(192 * 4);
    const size_t base = off;

    // KV-chunk size: prefer CT=8 (640 blocks), fall back if ws is tight.
    int ctLog = 5, MAXC = 1;
    const int cands[3] = {3, 4, 5};
    for (int ci = 0; ci < 3; ++ci) {
        const int cl = cands[ci];
        const int mc = (31 >> cl) + 1;
        const size_t nslot = (size_t)256 * mc;
        const size_t need = base + nslot * (4096 + 64) * 4 + 8192;
        if (need <= ws_size) { ctLog = cl; MAXC = mc; break; }
    }
    const size_t NSLOT = (size_t)256 * MAXC;
    float* Opart = (float*)alloc(NSLOT * 4096 * 4);
    float* lpart = (float*)alloc(NSLOT * 64 * 4);

    const int CT = 1 << ctLog;
    int NCperB = 0;
    for (int qt = 0; qt < 32; ++qt) NCperB += (qt + CT) >> ctLog;

    convw_kernel<<<256, 256, 0, stream>>>(Wq, bq, Wk, bk, Wv, bv, Wo, Wb, Wob, biasb);
    qkv_kernel<<<NM / 64, 512, 0, stream>>>(x, Wb, biasb, qb, kb, vtb);
    attn_kernel<<<8 * NCperB, 256, 0, stream>>>(qb, kb, vtb, Opart, lpart, ctLog, MAXC);
    combine_kernel<<<256, 256, 0, stream>>>(Opart, lpart, Wob, bo, out, ctLog, MAXC);
}